// Round 18
// baseline (333.329 us; speedup 1.0000x reference)
//
#include <hip/hip_runtime.h>
#include <hip/hip_bf16.h>

// TemporalAttention fused kernel for MI355X (gfx950), round 18.
// 256-THREAD BLOCKS (4 waves), one sequence per block, 2 heads per wave
// (sequential passes). Rationale: R17 proved occupancy is pinned by
// (arch+accumulator) registers (~180/wave -> 2 waves/SIMD) x the 8-wave
// block quantum -> exactly 1 block/CU in ALL 17 rounds. A 4-wave block
// makes 2-3 INDEPENDENT blocks/CU automatic at the same register level.
// Components: R16 merged sweep + middle + O^T scatter (verified), direct
// global wave-private weights (R13-A verified; sweeps barrier-free),
// NT streams (R14), 32KB LDS (X -> att -> f32 quarter overlays).

namespace {

constexpr int S_LEN = 64;
constexpr int DM    = 256;
constexpr int SD    = S_LEN * DM;
constexpr int NQKV  = 3 * DM * DM;

typedef float f32x4 __attribute__((ext_vector_type(4)));
typedef short s16x8 __attribute__((ext_vector_type(8)));

union BF2 { __hip_bfloat162 h; unsigned u; };
__device__ __forceinline__ unsigned pkbf2(float a, float b) {
  float2 t; t.x = a; t.y = b;
  BF2 cv; cv.h = __float22bfloat162_rn(t);
  return cv.u;
}

// lgkm-only block barrier (R11-verified).
__device__ __forceinline__ void bar_lgkm() {
  asm volatile("s_waitcnt lgkmcnt(0)" ::: "memory");
  __builtin_amdgcn_sched_barrier(0);
  __builtin_amdgcn_s_barrier();
  __builtin_amdgcn_sched_barrier(0);
}

// In-register fragment transpose (verified rounds 3-17).
__device__ __forceinline__ s16x8 xpose_frag(f32x4 a0, f32x4 a1, int c, int g) {
  const int src0 = ((g & 1) << 5) + c;
  const int src1 = src0 + 16;
  unsigned p00 = pkbf2(a0[0], a0[1]);
  unsigned p01 = pkbf2(a0[2], a0[3]);
  unsigned p10 = pkbf2(a1[0], a1[1]);
  unsigned p11 = pkbf2(a1[2], a1[3]);
  const bool hi = (g & 2) != 0;
  unsigned w0a = (unsigned)__shfl((int)p00, src0);
  unsigned w0b = (unsigned)__shfl((int)p10, src0);
  unsigned w1a = (unsigned)__shfl((int)p01, src0);
  unsigned w1b = (unsigned)__shfl((int)p11, src0);
  unsigned w2a = (unsigned)__shfl((int)p00, src1);
  unsigned w2b = (unsigned)__shfl((int)p10, src1);
  unsigned w3a = (unsigned)__shfl((int)p01, src1);
  unsigned w3b = (unsigned)__shfl((int)p11, src1);
  union { s16x8 v; unsigned u[4]; } r;
  r.u[0] = hi ? w0b : w0a;
  r.u[1] = hi ? w1b : w1a;
  r.u[2] = hi ? w2b : w2a;
  r.u[3] = hi ? w3b : w3a;
  return r.v;
}

} // namespace

// ---- prep: f32 weights -> bf16 in workspace (R11 verbatim) ----
__global__ void ta_prep_weights(const float* __restrict__ wqkv,
                                const float* __restrict__ wproj,
                                unsigned short* __restrict__ wsb) {
  const int i = (blockIdx.x * 256 + (int)threadIdx.x) * 4;
  f32x4 v = (i < NQKV) ? *(const f32x4*)(wqkv + i)
                       : *(const f32x4*)(wproj + (i - NQKV));
  unsigned u0 = pkbf2(v[0], v[1]);
  unsigned u1 = pkbf2(v[2], v[3]);
  *(uint2*)(wsb + i) = make_uint2(u0, u1);
}

__global__ void __launch_bounds__(256, 1)
ta_fused_kernel(const float* __restrict__ x,
                const unsigned short* __restrict__ wq_bf,   // [768][256] bf16
                const float* __restrict__ bqkv,
                const unsigned short* __restrict__ wp_bf,   // [256][256] bf16
                const float* __restrict__ bproj,
                float* __restrict__ out)
{
  // LDS 32KB: xls[64][256] bf16 (X, swizzled) -> att overlay
  //           -> f32 [16][256] epilogue quarters (16KB) overlay.
  __shared__ __align__(16) unsigned short lds[16384];

  const int bn = blockIdx.x;
  const int tid = (int)threadIdx.x;
  const int w = tid >> 6;       // wave 0..3
  const int l = tid & 63;
  const int g = l >> 4;
  const int c = l & 15;
  const int c7s = (c & 7) << 3;

  unsigned short* __restrict__ xls = lds;
  const float* __restrict__ xb = x + (size_t)bn * SD;

  // ---- stage X -> LDS bf16 (swizzled, NT loads; verified R6/R14) ----
#pragma unroll
  for (int it = 0; it < 8; ++it) {
    const int e = (it * 256 + tid) * 8;
    const int row = e >> 8;
    f32x4 a = __builtin_nontemporal_load((const f32x4*)(xb + e));
    f32x4 b = __builtin_nontemporal_load((const f32x4*)(xb + e + 4));
    union { s16x8 v; unsigned u[4]; } r;
    r.u[0] = pkbf2(a[0], a[1]); r.u[1] = pkbf2(a[2], a[3]);
    r.u[2] = pkbf2(b[0], b[1]); r.u[3] = pkbf2(b[2], b[3]);
    *(s16x8*)&xls[e ^ ((row & 7) << 3)] = r.v;
  }
  __syncthreads();   // X visible; sweeps below are barrier-free

  uint2 obp[2][2][4];   // [pass][nd][mi]

#pragma unroll
  for (int p = 0; p < 2; ++p) {
    const int h = 4 * p + w;   // head for this pass

    // ---- merged Q/K/V sweep, weights direct global (R13-A verified) ----
    f32x4 aq[2][4], ak[2][4], av[4][2];
#pragma unroll
    for (int t = 0; t < 2; ++t)
#pragma unroll
      for (int nj = 0; nj < 4; ++nj) {
        aq[t][nj] = f32x4{0.f, 0.f, 0.f, 0.f};
        ak[t][nj] = f32x4{0.f, 0.f, 0.f, 0.f};
      }
#pragma unroll
    for (int mt = 0; mt < 4; ++mt)
#pragma unroll
      for (int t = 0; t < 2; ++t) av[mt][t] = f32x4{0.f, 0.f, 0.f, 0.f};

#pragma unroll
    for (int ks = 0; ks < 8; ++ks) {
      const int kof = ks * 32 + g * 8;
      s16x8 bx[4];
#pragma unroll
      for (int nj = 0; nj < 4; ++nj) {
        const int row = 16 * nj + c;
        bx[nj] = *(const s16x8*)&xls[(row * 256 + kof) ^ c7s];
      }
#pragma unroll
      for (int t = 0; t < 2; ++t) {
        s16x8 awq = *(const s16x8*)&wq_bf[(size_t)((2 * h + t) * 16 + c) * DM + kof];
        s16x8 awk = *(const s16x8*)&wq_bf[(size_t)((256 + 32 * h + 16 * t) + c) * DM + kof];
        s16x8 awv = *(const s16x8*)&wq_bf[(size_t)(512 + 32 * h + 16 * t + c) * DM + kof];
#pragma unroll
        for (int nj = 0; nj < 4; ++nj) {
          aq[t][nj] = __builtin_amdgcn_mfma_f32_16x16x32_bf16(awq, bx[nj], aq[t][nj], 0, 0, 0);
          ak[t][nj] = __builtin_amdgcn_mfma_f32_16x16x32_bf16(awk, bx[nj], ak[t][nj], 0, 0, 0);
          av[nj][t] = __builtin_amdgcn_mfma_f32_16x16x32_bf16(bx[nj], awv, av[nj][t], 0, 0, 0);
        }
      }
    }

    // ---- biases ----
#pragma unroll
    for (int t = 0; t < 2; ++t) {
      f32x4 bq = *(const f32x4*)(bqkv + (2 * h + t) * 16 + 4 * g);
      f32x4 bk = *(const f32x4*)(bqkv + 256 + 32 * h + 16 * t + 4 * g);
#pragma unroll
      for (int nj = 0; nj < 4; ++nj) {
        aq[t][nj] += bq;
        ak[t][nj] += bk;
      }
    }
    {
      const float bv0 = bqkv[512 + 32 * h + c];
      const float bv1 = bqkv[512 + 32 * h + 16 + c];
#pragma unroll
      for (int mt = 0; mt < 4; ++mt)
#pragma unroll
        for (int r = 0; r < 4; ++r) {
          av[mt][0][r] += bv0;
          av[mt][1][r] += bv1;
        }
    }

    // ---- Q,K fragments ----
    s16x8 qa[4], ka[4];
#pragma unroll
    for (int i = 0; i < 4; ++i) {
      qa[i] = xpose_frag(aq[0][i], aq[1][i], c, g);
      ka[i] = xpose_frag(ak[0][i], ak[1][i], c, g);
    }

    // ---- S^T = K @ Q^T ----
    f32x4 sa[4][4];
#pragma unroll
    for (int ki = 0; ki < 4; ++ki)
#pragma unroll
      for (int qi = 0; qi < 4; ++qi) {
        f32x4 z = f32x4{0.f, 0.f, 0.f, 0.f};
        sa[ki][qi] = __builtin_amdgcn_mfma_f32_16x16x32_bf16(ka[ki], qa[qi], z, 0, 0, 0);
      }

    // ---- softmax over keys ----
    const float sc = 0.17677669529663687f * 1.4426950408889634f;
    float inv[4];
#pragma unroll
    for (int qi = 0; qi < 4; ++qi) {
      float m = sa[0][qi][0];
#pragma unroll
      for (int ki = 0; ki < 4; ++ki)
#pragma unroll
        for (int r = 0; r < 4; ++r) m = fmaxf(m, sa[ki][qi][r]);
      m = fmaxf(m, __shfl_xor(m, 16));
      m = fmaxf(m, __shfl_xor(m, 32));
      float s = 0.0f;
#pragma unroll
      for (int ki = 0; ki < 4; ++ki)
#pragma unroll
        for (int r = 0; r < 4; ++r) {
          float pv = exp2f((sa[ki][qi][r] - m) * sc);
          sa[ki][qi][r] = pv;
          s += pv;
        }
      s += __shfl_xor(s, 16);
      s += __shfl_xor(s, 32);
      inv[qi] = 1.0f / s;
    }

    // ---- P fragments ----
    s16x8 pa[4][2];
#pragma unroll
    for (int mi = 0; mi < 4; ++mi) {
      const float iv = inv[mi];
#pragma unroll
      for (int ks2 = 0; ks2 < 2; ++ks2) {
        f32x4 v0 = sa[2 * ks2][mi] * iv;
        f32x4 v1 = sa[2 * ks2 + 1][mi] * iv;
        pa[mi][ks2] = xpose_frag(v0, v1, c, g);
      }
    }

    // ---- V fragments ----
    s16x8 vb[2][2];
#pragma unroll
    for (int nd = 0; nd < 2; ++nd)
#pragma unroll
      for (int ks2 = 0; ks2 < 2; ++ks2)
        vb[nd][ks2] = xpose_frag(av[2 * ks2][nd], av[2 * ks2 + 1][nd], c, g);

    // ---- O^T = V^T @ P^T (R16-verified operand swap) ----
    f32x4 ot[2][4];
#pragma unroll
    for (int nd = 0; nd < 2; ++nd)
#pragma unroll
      for (int mi = 0; mi < 4; ++mi) ot[nd][mi] = f32x4{0.f, 0.f, 0.f, 0.f};
#pragma unroll
    for (int ks2 = 0; ks2 < 2; ++ks2)
#pragma unroll
      for (int nd = 0; nd < 2; ++nd)
#pragma unroll
        for (int mi = 0; mi < 4; ++mi)
          ot[nd][mi] = __builtin_amdgcn_mfma_f32_16x16x32_bf16(vb[nd][ks2], pa[mi][ks2], ot[nd][mi], 0, 0, 0);

#pragma unroll
    for (int nd = 0; nd < 2; ++nd)
#pragma unroll
      for (int mi = 0; mi < 4; ++mi) {
        obp[p][nd][mi].x = pkbf2(ot[nd][mi][0], ot[nd][mi][1]);
        obp[p][nd][mi].y = pkbf2(ot[nd][mi][2], ot[nd][mi][3]);
      }
  } // pass loop

  __syncthreads();   // all X reads done (both passes)

  // ---- scatter att over X region (vectorized b64, R16-verified) ----
#pragma unroll
  for (int p = 0; p < 2; ++p) {
    const int h = 4 * p + w;
#pragma unroll
    for (int nd = 0; nd < 2; ++nd)
#pragma unroll
      for (int mi = 0; mi < 4; ++mi) {
        const int q = 16 * mi + c;
        const int feat = h * 32 + 16 * nd + 4 * g;
        *(uint2*)&xls[(q * 256 + feat) ^ c7s] = obp[p][nd][mi];   // q&7 == c&7
      }
  }
  __syncthreads();   // att visible

  // ---- Phase C: out^T = Wproj @ att^T (4 e-tiles per wave, direct W) ----
  f32x4 pacc[4][4];
#pragma unroll
  for (int ti = 0; ti < 4; ++ti)
#pragma unroll
    for (int nj = 0; nj < 4; ++nj) pacc[ti][nj] = f32x4{0.f, 0.f, 0.f, 0.f};

#pragma unroll
  for (int ks = 0; ks < 8; ++ks) {
    const int kof = ks * 32 + 8 * g;
    s16x8 bx[4];
#pragma unroll
    for (int nj = 0; nj < 4; ++nj) {
      const int row = 16 * nj + c;
      bx[nj] = *(const s16x8*)&xls[(row * 256 + kof) ^ c7s];
    }
#pragma unroll
    for (int ti = 0; ti < 4; ++ti) {
      const int e = (4 * w + ti) * 16 + c;
      s16x8 aw = *(const s16x8*)&wp_bf[(size_t)e * DM + kof];
#pragma unroll
      for (int nj = 0; nj < 4; ++nj)
        pacc[ti][nj] = __builtin_amdgcn_mfma_f32_16x16x32_bf16(aw, bx[nj], pacc[ti][nj], 0, 0, 0);
    }
  }
  __syncthreads();   // att reads done; xls reusable as f32 quarters

  // ---- epilogue: four 16-row f32 quarters (16KB overlay), NT stores ----
  float* ldsf = (float*)lds;
  float* __restrict__ ob = out + (size_t)bn * SD;
#pragma unroll
  for (int H = 0; H < 4; ++H) {
    // quarter H = rows 16H..16H+15 = nj == H; local row = c
#pragma unroll
    for (int ti = 0; ti < 4; ++ti) {
      const int e0 = (4 * w + ti) * 16 + 4 * g;
      f32x4 bp = *(const f32x4*)(bproj + e0);
      f32x4 v;
      v[0] = pacc[ti][H][0] + bp[0];
      v[1] = pacc[ti][H][1] + bp[1];
      v[2] = pacc[ti][H][2] + bp[2];
      v[3] = pacc[ti][H][3] + bp[3];
      *(f32x4*)&ldsf[(c * 256 + e0) ^ ((c & 7) << 2)] = v;
    }
    bar_lgkm();
#pragma unroll
    for (int it = 0; it < 4; ++it) {
      const int i = (it * 256 + tid) * 4;   // [0, 4096)
      const int lr = i >> 8;
      f32x4 v = *(const f32x4*)&ldsf[i ^ ((lr & 7) << 2)];
      __builtin_nontemporal_store(v, (f32x4*)(ob + H * 4096 + i));
    }
    if (H < 3) bar_lgkm();
  }
}

extern "C" void kernel_launch(void* const* d_in, const int* in_sizes, int n_in,
                              void* d_out, int out_size, void* d_ws, size_t ws_size,
                              hipStream_t stream) {
  (void)n_in; (void)ws_size; (void)out_size;
  const float* x     = (const float*)d_in[0];
  const float* wqkv  = (const float*)d_in[1];
  const float* bqkv  = (const float*)d_in[2];
  const float* wproj = (const float*)d_in[3];
  const float* bproj = (const float*)d_in[4];
  float* out = (float*)d_out;

  unsigned short* wsb = (unsigned short*)d_ws;
  const unsigned short* wq_bf = wsb;
  const unsigned short* wp_bf = wsb + NQKV;

  hipLaunchKernelGGL(ta_prep_weights, dim3(256), dim3(256), 0, stream, wqkv, wproj, wsb);

  const int bn_total = in_sizes[0] / SD;  // 2600
  hipLaunchKernelGGL(ta_fused_kernel, dim3(bn_total), dim3(256), 0, stream,
                     x, wq_bf, bqkv, wp_bf, bproj, out);
}

// Round 19
// 251.280 us; speedup vs baseline: 1.3265x; 1.3265x over previous
//
#include <hip/hip_runtime.h>
#include <hip/hip_bf16.h>

// TemporalAttention fused kernel for MI355X (gfx950), round 19.
// = Round 16 (best: 253.3us kernel / 235.8 total) + T5 s_setprio(1) around
// every MFMA cluster (sweep bursts, S^T, PV, phaseC). Mechanism (m191):
// setprio pays when co-resident waves sit at DIFFERENT phases - R16's
// barrier-free sweep middle lets its 8 waves drift, so MFMA-entering waves
// get issue priority over waves doing LDS/shuffle work. Everything else
// (math, layout, schedule, launch config) is R16 verbatim.

namespace {

constexpr int S_LEN = 64;
constexpr int DM    = 256;
constexpr int SD    = S_LEN * DM;
constexpr int NQKV  = 3 * DM * DM;

typedef float f32x4 __attribute__((ext_vector_type(4)));
typedef short s16x8 __attribute__((ext_vector_type(8)));

union BF2 { __hip_bfloat162 h; unsigned u; };
__device__ __forceinline__ unsigned pkbf2(float a, float b) {
  float2 t; t.x = a; t.y = b;
  BF2 cv; cv.h = __float22bfloat162_rn(t);
  return cv.u;
}

// lgkm-only block barrier (R11-verified): does NOT drain vmcnt.
__device__ __forceinline__ void bar_lgkm() {
  asm volatile("s_waitcnt lgkmcnt(0)" ::: "memory");
  __builtin_amdgcn_sched_barrier(0);
  __builtin_amdgcn_s_barrier();
  __builtin_amdgcn_sched_barrier(0);
}

// In-register fragment transpose (verified rounds 3-18).
__device__ __forceinline__ s16x8 xpose_frag(f32x4 a0, f32x4 a1, int c, int g) {
  const int src0 = ((g & 1) << 5) + c;
  const int src1 = src0 + 16;
  unsigned p00 = pkbf2(a0[0], a0[1]);
  unsigned p01 = pkbf2(a0[2], a0[3]);
  unsigned p10 = pkbf2(a1[0], a1[1]);
  unsigned p11 = pkbf2(a1[2], a1[3]);
  const bool hi = (g & 2) != 0;
  unsigned w0a = (unsigned)__shfl((int)p00, src0);
  unsigned w0b = (unsigned)__shfl((int)p10, src0);
  unsigned w1a = (unsigned)__shfl((int)p01, src0);
  unsigned w1b = (unsigned)__shfl((int)p11, src0);
  unsigned w2a = (unsigned)__shfl((int)p00, src1);
  unsigned w2b = (unsigned)__shfl((int)p10, src1);
  unsigned w3a = (unsigned)__shfl((int)p01, src1);
  unsigned w3b = (unsigned)__shfl((int)p11, src1);
  union { s16x8 v; unsigned u[4]; } r;
  r.u[0] = hi ? w0b : w0a;
  r.u[1] = hi ? w1b : w1a;
  r.u[2] = hi ? w2b : w2a;
  r.u[3] = hi ? w3b : w3a;
  return r.v;
}

// Weight LDS addressing (verified R9-R18): per-ks image [rows][32 cols] bf16,
// 16B-unit swizzle u' = g ^ ((row>>1)&3) => 2-way aliasing (free, m136).
__device__ __forceinline__ int wswz(int row, int u) {
  return row * 32 + ((u ^ ((row >> 1) & 3)) << 3);
}

} // namespace

// ---- prep: f32 weights -> bf16 in workspace ----
__global__ void ta_prep_weights(const float* __restrict__ wqkv,
                                const float* __restrict__ wproj,
                                unsigned short* __restrict__ wsb) {
  const int i = (blockIdx.x * 256 + (int)threadIdx.x) * 4;
  f32x4 v = (i < NQKV) ? *(const f32x4*)(wqkv + i)
                       : *(const f32x4*)(wproj + (i - NQKV));
  unsigned u0 = pkbf2(v[0], v[1]);
  unsigned u1 = pkbf2(v[2], v[3]);
  *(uint2*)(wsb + i) = make_uint2(u0, u1);
}

__global__ void __launch_bounds__(512, 1)
ta_fused_kernel(const float* __restrict__ x,
                const unsigned short* __restrict__ wq_bf,   // [768][256] bf16
                const float* __restrict__ bqkv,
                const unsigned short* __restrict__ wp_bf,   // [256][256] bf16
                const float* __restrict__ bproj,
                float* __restrict__ out)
{
  // LDS 128KB (65536 shorts):
  //  [0,16384)      xls[64][256] bf16 X (swizzled) -> att overlay
  //  [16384,40960)  W stage buffer 0 (48KB: [768][32] per-ks image)
  //  [40960,65536)  W stage buffer 1
  //  epilogue: f32 [32][256] overlay on buffer-0 region
  __shared__ __align__(16) unsigned short lds[65536];

  const int bn = blockIdx.x;
  const int tid = (int)threadIdx.x;
  const int w = tid >> 6;       // wave 0..7 = head
  const int l = tid & 63;
  const int g = l >> 4;
  const int c = l & 15;
  const int c7s = (c & 7) << 3;
  const int h = w;

  unsigned short* __restrict__ xls = lds;
  unsigned short* wbuf[2] = { lds + 16384, lds + 40960 };

  const float* __restrict__ xb = x + (size_t)bn * SD;

  // ---- issue W[ks=0] staging loads (fly under X stage) ----
  s16x8 wst[6];
#pragma unroll
  for (int i = 0; i < 6; ++i) {
    const int idx = i * 512 + tid, row = idx >> 2, gl = idx & 3;
    wst[i] = *(const s16x8*)&wq_bf[row * 256 + 0 * 32 + gl * 8];
  }

  // ---- stage X -> LDS bf16 (swizzled; NT loads: don't thrash L2) ----
#pragma unroll
  for (int it = 0; it < 4; ++it) {
    const int e = (it * 512 + tid) * 8;
    const int row = e >> 8;
    f32x4 a = __builtin_nontemporal_load((const f32x4*)(xb + e));
    f32x4 b = __builtin_nontemporal_load((const f32x4*)(xb + e + 4));
    union { s16x8 v; unsigned u[4]; } r;
    r.u[0] = pkbf2(a[0], a[1]); r.u[1] = pkbf2(a[2], a[3]);
    r.u[2] = pkbf2(b[0], b[1]); r.u[3] = pkbf2(b[2], b[3]);
    *(s16x8*)&xls[e ^ ((row & 7) << 3)] = r.v;
  }
  bar_lgkm();                      // X visible; wst0 loads still in flight

  // ---- W prologue: write buf0 = W[0]; issue W[1] ----
#pragma unroll
  for (int i = 0; i < 6; ++i) {
    const int idx = i * 512 + tid, row = idx >> 2, gl = idx & 3;
    *(s16x8*)&wbuf[0][wswz(row, gl)] = wst[i];
  }
#pragma unroll
  for (int i = 0; i < 6; ++i) {
    const int idx = i * 512 + tid, row = idx >> 2, gl = idx & 3;
    wst[i] = *(const s16x8*)&wq_bf[row * 256 + 1 * 32 + gl * 8];
  }
  bar_lgkm();                      // buf0 ready; W1 loads in flight

  // ---- merged Q/K/V sweep: 8 ks-steps, lgkm-only barriers ----
  f32x4 aq[2][4], ak[2][4], av[4][2];
#pragma unroll
  for (int t = 0; t < 2; ++t)
#pragma unroll
    for (int nj = 0; nj < 4; ++nj) {
      aq[t][nj] = f32x4{0.f, 0.f, 0.f, 0.f};
      ak[t][nj] = f32x4{0.f, 0.f, 0.f, 0.f};
    }
#pragma unroll
  for (int mt = 0; mt < 4; ++mt)
#pragma unroll
    for (int t = 0; t < 2; ++t) av[mt][t] = f32x4{0.f, 0.f, 0.f, 0.f};

#pragma unroll
  for (int ks = 0; ks < 8; ++ks) {
    const unsigned short* wb = wbuf[ks & 1];
    const int kof = ks * 32 + g * 8;
    s16x8 bx[4];
#pragma unroll
    for (int nj = 0; nj < 4; ++nj) {
      const int row = 16 * nj + c;
      bx[nj] = *(const s16x8*)&xls[(row * 256 + kof) ^ c7s];
    }
#pragma unroll
    for (int t = 0; t < 2; ++t) {
      s16x8 awq = *(const s16x8*)&wb[wswz((2 * h + t) * 16 + c, g)];
      s16x8 awk = *(const s16x8*)&wb[wswz(256 + 32 * h + 16 * t + c, g)];
      s16x8 awv = *(const s16x8*)&wb[wswz(512 + 32 * h + 16 * t + c, g)];
      __builtin_amdgcn_s_setprio(1);
#pragma unroll
      for (int nj = 0; nj < 4; ++nj) {
        aq[t][nj] = __builtin_amdgcn_mfma_f32_16x16x32_bf16(awq, bx[nj], aq[t][nj], 0, 0, 0);
        ak[t][nj] = __builtin_amdgcn_mfma_f32_16x16x32_bf16(awk, bx[nj], ak[t][nj], 0, 0, 0);
        av[nj][t] = __builtin_amdgcn_mfma_f32_16x16x32_bf16(bx[nj], awv, av[nj][t], 0, 0, 0);
      }
      __builtin_amdgcn_s_setprio(0);
    }
    if (ks < 7) {   // write next buffer (counted vmcnt wait, not 0)
#pragma unroll
      for (int i = 0; i < 6; ++i) {
        const int idx = i * 512 + tid, row = idx >> 2, gl = idx & 3;
        *(s16x8*)&wbuf[(ks + 1) & 1][wswz(row, gl)] = wst[i];
      }
    }
    if (ks < 6) {   // issue loads for ks+2 (stay in flight across barrier)
#pragma unroll
      for (int i = 0; i < 6; ++i) {
        const int idx = i * 512 + tid, row = idx >> 2, gl = idx & 3;
        wst[i] = *(const s16x8*)&wq_bf[row * 256 + (ks + 2) * 32 + gl * 8];
      }
    }
    bar_lgkm();
  }

  // ---- issue phaseC W[0] loads early (fly under the attention middle) ----
  s16x8 pst[2];
#pragma unroll
  for (int i = 0; i < 2; ++i) {
    const int idx = i * 512 + tid, row = idx >> 2, gl = idx & 3;
    pst[i] = *(const s16x8*)&wp_bf[row * 256 + 0 * 32 + gl * 8];
  }

  // ---- biases ----
#pragma unroll
  for (int t = 0; t < 2; ++t) {
    f32x4 bq = *(const f32x4*)(bqkv + (2 * h + t) * 16 + 4 * g);
    f32x4 bk = *(const f32x4*)(bqkv + 256 + 32 * h + 16 * t + 4 * g);
#pragma unroll
    for (int nj = 0; nj < 4; ++nj) {
      aq[t][nj] += bq;
      ak[t][nj] += bk;
    }
  }
  {
    const float bv0 = bqkv[512 + 32 * h + c];
    const float bv1 = bqkv[512 + 32 * h + 16 + c];
#pragma unroll
    for (int mt = 0; mt < 4; ++mt)
#pragma unroll
      for (int r = 0; r < 4; ++r) {
        av[mt][0][r] += bv0;
        av[mt][1][r] += bv1;
      }
  }

  // ---- Q,K fragments (in-register transpose) ----
  s16x8 qa[4], ka[4];
#pragma unroll
  for (int i = 0; i < 4; ++i) {
    qa[i] = xpose_frag(aq[0][i], aq[1][i], c, g);
    ka[i] = xpose_frag(ak[0][i], ak[1][i], c, g);
  }

  // ---- S^T = K @ Q^T ----
  f32x4 sa[4][4];
  __builtin_amdgcn_s_setprio(1);
#pragma unroll
  for (int ki = 0; ki < 4; ++ki)
#pragma unroll
    for (int qi = 0; qi < 4; ++qi) {
      f32x4 z = f32x4{0.f, 0.f, 0.f, 0.f};
      sa[ki][qi] = __builtin_amdgcn_mfma_f32_16x16x32_bf16(ka[ki], qa[qi], z, 0, 0, 0);
    }
  __builtin_amdgcn_s_setprio(0);

  // ---- softmax over keys ----
  const float sc = 0.17677669529663687f * 1.4426950408889634f;
  float inv[4];
#pragma unroll
  for (int qi = 0; qi < 4; ++qi) {
    float m = sa[0][qi][0];
#pragma unroll
    for (int ki = 0; ki < 4; ++ki)
#pragma unroll
      for (int r = 0; r < 4; ++r) m = fmaxf(m, sa[ki][qi][r]);
    m = fmaxf(m, __shfl_xor(m, 16));
    m = fmaxf(m, __shfl_xor(m, 32));
    float s = 0.0f;
#pragma unroll
    for (int ki = 0; ki < 4; ++ki)
#pragma unroll
      for (int r = 0; r < 4; ++r) {
        float pv = exp2f((sa[ki][qi][r] - m) * sc);
        sa[ki][qi][r] = pv;
        s += pv;
      }
    s += __shfl_xor(s, 16);
    s += __shfl_xor(s, 32);
    inv[qi] = 1.0f / s;
  }

  // ---- P fragments ----
  s16x8 pa[4][2];
#pragma unroll
  for (int mi = 0; mi < 4; ++mi) {
    const float iv = inv[mi];
#pragma unroll
    for (int ks2 = 0; ks2 < 2; ++ks2) {
      f32x4 v0 = sa[2 * ks2][mi] * iv;
      f32x4 v1 = sa[2 * ks2 + 1][mi] * iv;
      pa[mi][ks2] = xpose_frag(v0, v1, c, g);
    }
  }

  // ---- V fragments ----
  s16x8 vb[2][2];
#pragma unroll
  for (int nd = 0; nd < 2; ++nd)
#pragma unroll
    for (int ks2 = 0; ks2 < 2; ++ks2)
      vb[nd][ks2] = xpose_frag(av[2 * ks2][nd], av[2 * ks2 + 1][nd], c, g);

  // ---- O^T = V^T @ P^T (R16-verified operand swap) ----
  f32x4 ot[2][4];
#pragma unroll
  for (int nd = 0; nd < 2; ++nd)
#pragma unroll
    for (int mi = 0; mi < 4; ++mi) ot[nd][mi] = f32x4{0.f, 0.f, 0.f, 0.f};
  __builtin_amdgcn_s_setprio(1);
#pragma unroll
  for (int ks2 = 0; ks2 < 2; ++ks2)
#pragma unroll
    for (int nd = 0; nd < 2; ++nd)
#pragma unroll
      for (int mi = 0; mi < 4; ++mi)
        ot[nd][mi] = __builtin_amdgcn_mfma_f32_16x16x32_bf16(vb[nd][ks2], pa[mi][ks2], ot[nd][mi], 0, 0, 0);
  __builtin_amdgcn_s_setprio(0);

  // pack: lane owns att[q = 16mi+c][feat = h*32 + 16nd + 4g .. +3]
  uint2 obp[2][4];
#pragma unroll
  for (int nd = 0; nd < 2; ++nd)
#pragma unroll
    for (int mi = 0; mi < 4; ++mi) {
      obp[nd][mi].x = pkbf2(ot[nd][mi][0], ot[nd][mi][1]);
      obp[nd][mi].y = pkbf2(ot[nd][mi][2], ot[nd][mi][3]);
    }

  // ---- scatter att over X region (vectorized b64, 2-way banks);
  //      stage phaseC buf0; one barrier ----
#pragma unroll
  for (int nd = 0; nd < 2; ++nd)
#pragma unroll
    for (int mi = 0; mi < 4; ++mi) {
      const int q = 16 * mi + c;
      const int feat = h * 32 + 16 * nd + 4 * g;
      *(uint2*)&xls[(q * 256 + feat) ^ c7s] = obp[nd][mi];   // q&7 == c&7
    }
#pragma unroll
  for (int i = 0; i < 2; ++i) {
    const int idx = i * 512 + tid, row = idx >> 2, gl = idx & 3;
    *(s16x8*)&wbuf[0][wswz(row, gl)] = pst[i];
  }
#pragma unroll
  for (int i = 0; i < 2; ++i) {
    const int idx = i * 512 + tid, row = idx >> 2, gl = idx & 3;
    pst[i] = *(const s16x8*)&wp_bf[row * 256 + 1 * 32 + gl * 8];
  }
  bar_lgkm();                      // att + phaseC buf0 visible; P1 in flight

  // ---- Phase C: out^T = Wproj @ att^T, weights from staged LDS ----
  f32x4 pacc[2][4];
#pragma unroll
  for (int ti = 0; ti < 2; ++ti)
#pragma unroll
    for (int nj = 0; nj < 4; ++nj) pacc[ti][nj] = f32x4{0.f, 0.f, 0.f, 0.f};

#pragma unroll
  for (int ks = 0; ks < 8; ++ks) {
    const unsigned short* wb = wbuf[ks & 1];
    const int kof = ks * 32 + 8 * g;
    s16x8 bx[4];
#pragma unroll
    for (int nj = 0; nj < 4; ++nj) {
      const int row = 16 * nj + c;
      bx[nj] = *(const s16x8*)&xls[(row * 256 + kof) ^ c7s];
    }
#pragma unroll
    for (int ti = 0; ti < 2; ++ti) {
      s16x8 aw = *(const s16x8*)&wb[wswz((2 * w + ti) * 16 + c, g)];
      __builtin_amdgcn_s_setprio(1);
#pragma unroll
      for (int nj = 0; nj < 4; ++nj)
        pacc[ti][nj] = __builtin_amdgcn_mfma_f32_16x16x32_bf16(aw, bx[nj], pacc[ti][nj], 0, 0, 0);
      __builtin_amdgcn_s_setprio(0);
    }
    if (ks < 7) {
#pragma unroll
      for (int i = 0; i < 2; ++i) {
        const int idx = i * 512 + tid, row = idx >> 2, gl = idx & 3;
        *(s16x8*)&wbuf[(ks + 1) & 1][wswz(row, gl)] = pst[i];
      }
    }
    if (ks < 6) {
#pragma unroll
      for (int i = 0; i < 2; ++i) {
        const int idx = i * 512 + tid, row = idx >> 2, gl = idx & 3;
        pst[i] = *(const s16x8*)&wp_bf[row * 256 + (ks + 2) * 32 + gl * 8];
      }
    }
    bar_lgkm();
  }

  // ---- epilogue: two 32-row f32 halves (overlay W buf0), NT stores ----
  float* ldsf = (float*)wbuf[0];
  float* __restrict__ ob = out + (size_t)bn * SD;
#pragma unroll
  for (int H = 0; H < 2; ++H) {
#pragma unroll
    for (int ti = 0; ti < 2; ++ti) {
      const int e0 = (2 * w + ti) * 16 + 4 * g;
      f32x4 bp = *(const f32x4*)(bproj + e0);
#pragma unroll
      for (int nj = 2 * H; nj < 2 * H + 2; ++nj) {
        const int lr = 16 * (nj - 2 * H) + c;
        f32x4 v;
        v[0] = pacc[ti][nj][0] + bp[0];
        v[1] = pacc[ti][nj][1] + bp[1];
        v[2] = pacc[ti][nj][2] + bp[2];
        v[3] = pacc[ti][nj][3] + bp[3];
        *(f32x4*)&ldsf[(lr * 256 + e0) ^ ((lr & 7) << 2)] = v;
      }
    }
    bar_lgkm();
#pragma unroll
    for (int it = 0; it < 4; ++it) {
      const int i = (it * 512 + tid) * 4;
      const int lr = i >> 8;
      f32x4 v = *(const f32x4*)&ldsf[i ^ ((lr & 7) << 2)];
      __builtin_nontemporal_store(v, (f32x4*)(ob + H * 8192 + i));
    }
    if (H == 0) bar_lgkm();
  }
}

extern "C" void kernel_launch(void* const* d_in, const int* in_sizes, int n_in,
                              void* d_out, int out_size, void* d_ws, size_t ws_size,
                              hipStream_t stream) {
  (void)n_in; (void)ws_size; (void)out_size;
  const float* x     = (const float*)d_in[0];
  const float* wqkv  = (const float*)d_in[1];
  const float* bqkv  = (const float*)d_in[2];
  const float* wproj = (const float*)d_in[3];
  const float* bproj = (const float*)d_in[4];
  float* out = (float*)d_out;

  unsigned short* wsb = (unsigned short*)d_ws;
  const unsigned short* wq_bf = wsb;
  const unsigned short* wp_bf = wsb + NQKV;

  hipLaunchKernelGGL(ta_prep_weights, dim3(256), dim3(256), 0, stream, wqkv, wproj, wsb);

  const int bn_total = in_sizes[0] / SD;  // 2600
  hipLaunchKernelGGL(ta_fused_kernel, dim3(bn_total), dim3(512), 0, stream,
                     x, wq_bf, bqkv, wp_bf, bproj, out);
}

// Round 20
// 236.137 us; speedup vs baseline: 1.4116x; 1.0641x over previous
//
#include <hip/hip_runtime.h>
#include <hip/hip_bf16.h>

// TemporalAttention fused kernel for MI355X (gfx950), round 20.
// = Round 16 (best: 253.3us kernel / 235.8us total) with:
//  - setprio removed (R19 measured it -6%: barrier-coupled waves give the
//    scheduler nothing to arbitrate; toggling only perturbed issue).
//  - Epilogue merged: after phaseC's last barrier BOTH W buffers (96KB) are
//    dead, so the full 64KB f32 out-tile is written at once -> ONE barrier
//    (was 3) and 8 consecutive NT f32x4 stores (deeper store pipelining).
// Everything else (math, layouts, schedule, NT hints, launch config) is
// R16 verbatim.

namespace {

constexpr int S_LEN = 64;
constexpr int DM    = 256;
constexpr int SD    = S_LEN * DM;
constexpr int NQKV  = 3 * DM * DM;

typedef float f32x4 __attribute__((ext_vector_type(4)));
typedef short s16x8 __attribute__((ext_vector_type(8)));

union BF2 { __hip_bfloat162 h; unsigned u; };
__device__ __forceinline__ unsigned pkbf2(float a, float b) {
  float2 t; t.x = a; t.y = b;
  BF2 cv; cv.h = __float22bfloat162_rn(t);
  return cv.u;
}

// lgkm-only block barrier (R11-verified): does NOT drain vmcnt.
__device__ __forceinline__ void bar_lgkm() {
  asm volatile("s_waitcnt lgkmcnt(0)" ::: "memory");
  __builtin_amdgcn_sched_barrier(0);
  __builtin_amdgcn_s_barrier();
  __builtin_amdgcn_sched_barrier(0);
}

// In-register fragment transpose (verified rounds 3-19).
__device__ __forceinline__ s16x8 xpose_frag(f32x4 a0, f32x4 a1, int c, int g) {
  const int src0 = ((g & 1) << 5) + c;
  const int src1 = src0 + 16;
  unsigned p00 = pkbf2(a0[0], a0[1]);
  unsigned p01 = pkbf2(a0[2], a0[3]);
  unsigned p10 = pkbf2(a1[0], a1[1]);
  unsigned p11 = pkbf2(a1[2], a1[3]);
  const bool hi = (g & 2) != 0;
  unsigned w0a = (unsigned)__shfl((int)p00, src0);
  unsigned w0b = (unsigned)__shfl((int)p10, src0);
  unsigned w1a = (unsigned)__shfl((int)p01, src0);
  unsigned w1b = (unsigned)__shfl((int)p11, src0);
  unsigned w2a = (unsigned)__shfl((int)p00, src1);
  unsigned w2b = (unsigned)__shfl((int)p10, src1);
  unsigned w3a = (unsigned)__shfl((int)p01, src1);
  unsigned w3b = (unsigned)__shfl((int)p11, src1);
  union { s16x8 v; unsigned u[4]; } r;
  r.u[0] = hi ? w0b : w0a;
  r.u[1] = hi ? w1b : w1a;
  r.u[2] = hi ? w2b : w2a;
  r.u[3] = hi ? w3b : w3a;
  return r.v;
}

// Weight LDS addressing (verified R9-R19): per-ks image [rows][32 cols] bf16,
// 16B-unit swizzle u' = g ^ ((row>>1)&3) => 2-way aliasing (free, m136).
__device__ __forceinline__ int wswz(int row, int u) {
  return row * 32 + ((u ^ ((row >> 1) & 3)) << 3);
}

} // namespace

// ---- prep: f32 weights -> bf16 in workspace ----
__global__ void ta_prep_weights(const float* __restrict__ wqkv,
                                const float* __restrict__ wproj,
                                unsigned short* __restrict__ wsb) {
  const int i = (blockIdx.x * 256 + (int)threadIdx.x) * 4;
  f32x4 v = (i < NQKV) ? *(const f32x4*)(wqkv + i)
                       : *(const f32x4*)(wproj + (i - NQKV));
  unsigned u0 = pkbf2(v[0], v[1]);
  unsigned u1 = pkbf2(v[2], v[3]);
  *(uint2*)(wsb + i) = make_uint2(u0, u1);
}

__global__ void __launch_bounds__(512, 1)
ta_fused_kernel(const float* __restrict__ x,
                const unsigned short* __restrict__ wq_bf,   // [768][256] bf16
                const float* __restrict__ bqkv,
                const unsigned short* __restrict__ wp_bf,   // [256][256] bf16
                const float* __restrict__ bproj,
                float* __restrict__ out)
{
  // LDS 128KB (65536 shorts):
  //  [0,16384)      xls[64][256] bf16 X (swizzled) -> att overlay
  //  [16384,40960)  W stage buffer 0 (48KB: [768][32] per-ks image)
  //  [40960,65536)  W stage buffer 1
  //  epilogue: full f32 [64][256] tile (64KB) overlays both W buffers
  __shared__ __align__(16) unsigned short lds[65536];

  const int bn = blockIdx.x;
  const int tid = (int)threadIdx.x;
  const int w = tid >> 6;       // wave 0..7 = head
  const int l = tid & 63;
  const int g = l >> 4;
  const int c = l & 15;
  const int c7s = (c & 7) << 3;
  const int h = w;

  unsigned short* __restrict__ xls = lds;
  unsigned short* wbuf[2] = { lds + 16384, lds + 40960 };

  const float* __restrict__ xb = x + (size_t)bn * SD;

  // ---- issue W[ks=0] staging loads (fly under X stage) ----
  s16x8 wst[6];
#pragma unroll
  for (int i = 0; i < 6; ++i) {
    const int idx = i * 512 + tid, row = idx >> 2, gl = idx & 3;
    wst[i] = *(const s16x8*)&wq_bf[row * 256 + 0 * 32 + gl * 8];
  }

  // ---- stage X -> LDS bf16 (swizzled; NT loads: don't thrash L2) ----
#pragma unroll
  for (int it = 0; it < 4; ++it) {
    const int e = (it * 512 + tid) * 8;
    const int row = e >> 8;
    f32x4 a = __builtin_nontemporal_load((const f32x4*)(xb + e));
    f32x4 b = __builtin_nontemporal_load((const f32x4*)(xb + e + 4));
    union { s16x8 v; unsigned u[4]; } r;
    r.u[0] = pkbf2(a[0], a[1]); r.u[1] = pkbf2(a[2], a[3]);
    r.u[2] = pkbf2(b[0], b[1]); r.u[3] = pkbf2(b[2], b[3]);
    *(s16x8*)&xls[e ^ ((row & 7) << 3)] = r.v;
  }
  bar_lgkm();                      // X visible; wst0 loads still in flight

  // ---- W prologue: write buf0 = W[0]; issue W[1] ----
#pragma unroll
  for (int i = 0; i < 6; ++i) {
    const int idx = i * 512 + tid, row = idx >> 2, gl = idx & 3;
    *(s16x8*)&wbuf[0][wswz(row, gl)] = wst[i];
  }
#pragma unroll
  for (int i = 0; i < 6; ++i) {
    const int idx = i * 512 + tid, row = idx >> 2, gl = idx & 3;
    wst[i] = *(const s16x8*)&wq_bf[row * 256 + 1 * 32 + gl * 8];
  }
  bar_lgkm();                      // buf0 ready; W1 loads in flight

  // ---- merged Q/K/V sweep: 8 ks-steps, lgkm-only barriers ----
  f32x4 aq[2][4], ak[2][4], av[4][2];
#pragma unroll
  for (int t = 0; t < 2; ++t)
#pragma unroll
    for (int nj = 0; nj < 4; ++nj) {
      aq[t][nj] = f32x4{0.f, 0.f, 0.f, 0.f};
      ak[t][nj] = f32x4{0.f, 0.f, 0.f, 0.f};
    }
#pragma unroll
  for (int mt = 0; mt < 4; ++mt)
#pragma unroll
    for (int t = 0; t < 2; ++t) av[mt][t] = f32x4{0.f, 0.f, 0.f, 0.f};

#pragma unroll
  for (int ks = 0; ks < 8; ++ks) {
    const unsigned short* wb = wbuf[ks & 1];
    const int kof = ks * 32 + g * 8;
    s16x8 bx[4];
#pragma unroll
    for (int nj = 0; nj < 4; ++nj) {
      const int row = 16 * nj + c;
      bx[nj] = *(const s16x8*)&xls[(row * 256 + kof) ^ c7s];
    }
#pragma unroll
    for (int t = 0; t < 2; ++t) {
      s16x8 awq = *(const s16x8*)&wb[wswz((2 * h + t) * 16 + c, g)];
      s16x8 awk = *(const s16x8*)&wb[wswz(256 + 32 * h + 16 * t + c, g)];
      s16x8 awv = *(const s16x8*)&wb[wswz(512 + 32 * h + 16 * t + c, g)];
#pragma unroll
      for (int nj = 0; nj < 4; ++nj) {
        aq[t][nj] = __builtin_amdgcn_mfma_f32_16x16x32_bf16(awq, bx[nj], aq[t][nj], 0, 0, 0);
        ak[t][nj] = __builtin_amdgcn_mfma_f32_16x16x32_bf16(awk, bx[nj], ak[t][nj], 0, 0, 0);
        av[nj][t] = __builtin_amdgcn_mfma_f32_16x16x32_bf16(bx[nj], awv, av[nj][t], 0, 0, 0);
      }
    }
    if (ks < 7) {   // write next buffer (counted vmcnt wait, not 0)
#pragma unroll
      for (int i = 0; i < 6; ++i) {
        const int idx = i * 512 + tid, row = idx >> 2, gl = idx & 3;
        *(s16x8*)&wbuf[(ks + 1) & 1][wswz(row, gl)] = wst[i];
      }
    }
    if (ks < 6) {   // issue loads for ks+2 (stay in flight across barrier)
#pragma unroll
      for (int i = 0; i < 6; ++i) {
        const int idx = i * 512 + tid, row = idx >> 2, gl = idx & 3;
        wst[i] = *(const s16x8*)&wq_bf[row * 256 + (ks + 2) * 32 + gl * 8];
      }
    }
    bar_lgkm();
  }

  // ---- issue phaseC W[0] loads early (fly under the attention middle) ----
  s16x8 pst[2];
#pragma unroll
  for (int i = 0; i < 2; ++i) {
    const int idx = i * 512 + tid, row = idx >> 2, gl = idx & 3;
    pst[i] = *(const s16x8*)&wp_bf[row * 256 + 0 * 32 + gl * 8];
  }

  // ---- biases ----
#pragma unroll
  for (int t = 0; t < 2; ++t) {
    f32x4 bq = *(const f32x4*)(bqkv + (2 * h + t) * 16 + 4 * g);
    f32x4 bk = *(const f32x4*)(bqkv + 256 + 32 * h + 16 * t + 4 * g);
#pragma unroll
    for (int nj = 0; nj < 4; ++nj) {
      aq[t][nj] += bq;
      ak[t][nj] += bk;
    }
  }
  {
    const float bv0 = bqkv[512 + 32 * h + c];
    const float bv1 = bqkv[512 + 32 * h + 16 + c];
#pragma unroll
    for (int mt = 0; mt < 4; ++mt)
#pragma unroll
      for (int r = 0; r < 4; ++r) {
        av[mt][0][r] += bv0;
        av[mt][1][r] += bv1;
      }
  }

  // ---- Q,K fragments (in-register transpose) ----
  s16x8 qa[4], ka[4];
#pragma unroll
  for (int i = 0; i < 4; ++i) {
    qa[i] = xpose_frag(aq[0][i], aq[1][i], c, g);
    ka[i] = xpose_frag(ak[0][i], ak[1][i], c, g);
  }

  // ---- S^T = K @ Q^T ----
  f32x4 sa[4][4];
#pragma unroll
  for (int ki = 0; ki < 4; ++ki)
#pragma unroll
    for (int qi = 0; qi < 4; ++qi) {
      f32x4 z = f32x4{0.f, 0.f, 0.f, 0.f};
      sa[ki][qi] = __builtin_amdgcn_mfma_f32_16x16x32_bf16(ka[ki], qa[qi], z, 0, 0, 0);
    }

  // ---- softmax over keys ----
  const float sc = 0.17677669529663687f * 1.4426950408889634f;
  float inv[4];
#pragma unroll
  for (int qi = 0; qi < 4; ++qi) {
    float m = sa[0][qi][0];
#pragma unroll
    for (int ki = 0; ki < 4; ++ki)
#pragma unroll
      for (int r = 0; r < 4; ++r) m = fmaxf(m, sa[ki][qi][r]);
    m = fmaxf(m, __shfl_xor(m, 16));
    m = fmaxf(m, __shfl_xor(m, 32));
    float s = 0.0f;
#pragma unroll
    for (int ki = 0; ki < 4; ++ki)
#pragma unroll
      for (int r = 0; r < 4; ++r) {
        float pv = exp2f((sa[ki][qi][r] - m) * sc);
        sa[ki][qi][r] = pv;
        s += pv;
      }
    s += __shfl_xor(s, 16);
    s += __shfl_xor(s, 32);
    inv[qi] = 1.0f / s;
  }

  // ---- P fragments ----
  s16x8 pa[4][2];
#pragma unroll
  for (int mi = 0; mi < 4; ++mi) {
    const float iv = inv[mi];
#pragma unroll
    for (int ks2 = 0; ks2 < 2; ++ks2) {
      f32x4 v0 = sa[2 * ks2][mi] * iv;
      f32x4 v1 = sa[2 * ks2 + 1][mi] * iv;
      pa[mi][ks2] = xpose_frag(v0, v1, c, g);
    }
  }

  // ---- V fragments ----
  s16x8 vb[2][2];
#pragma unroll
  for (int nd = 0; nd < 2; ++nd)
#pragma unroll
    for (int ks2 = 0; ks2 < 2; ++ks2)
      vb[nd][ks2] = xpose_frag(av[2 * ks2][nd], av[2 * ks2 + 1][nd], c, g);

  // ---- O^T = V^T @ P^T (R16-verified operand swap) ----
  f32x4 ot[2][4];
#pragma unroll
  for (int nd = 0; nd < 2; ++nd)
#pragma unroll
    for (int mi = 0; mi < 4; ++mi) ot[nd][mi] = f32x4{0.f, 0.f, 0.f, 0.f};
#pragma unroll
  for (int ks2 = 0; ks2 < 2; ++ks2)
#pragma unroll
    for (int nd = 0; nd < 2; ++nd)
#pragma unroll
      for (int mi = 0; mi < 4; ++mi)
        ot[nd][mi] = __builtin_amdgcn_mfma_f32_16x16x32_bf16(vb[nd][ks2], pa[mi][ks2], ot[nd][mi], 0, 0, 0);

  // pack: lane owns att[q = 16mi+c][feat = h*32 + 16nd + 4g .. +3]
  uint2 obp[2][4];
#pragma unroll
  for (int nd = 0; nd < 2; ++nd)
#pragma unroll
    for (int mi = 0; mi < 4; ++mi) {
      obp[nd][mi].x = pkbf2(ot[nd][mi][0], ot[nd][mi][1]);
      obp[nd][mi].y = pkbf2(ot[nd][mi][2], ot[nd][mi][3]);
    }

  // ---- scatter att over X region (vectorized b64, 2-way banks);
  //      stage phaseC buf0; one barrier ----
#pragma unroll
  for (int nd = 0; nd < 2; ++nd)
#pragma unroll
    for (int mi = 0; mi < 4; ++mi) {
      const int q = 16 * mi + c;
      const int feat = h * 32 + 16 * nd + 4 * g;
      *(uint2*)&xls[(q * 256 + feat) ^ c7s] = obp[nd][mi];   // q&7 == c&7
    }
#pragma unroll
  for (int i = 0; i < 2; ++i) {
    const int idx = i * 512 + tid, row = idx >> 2, gl = idx & 3;
    *(s16x8*)&wbuf[0][wswz(row, gl)] = pst[i];
  }
#pragma unroll
  for (int i = 0; i < 2; ++i) {
    const int idx = i * 512 + tid, row = idx >> 2, gl = idx & 3;
    pst[i] = *(const s16x8*)&wp_bf[row * 256 + 1 * 32 + gl * 8];
  }
  bar_lgkm();                      // att + phaseC buf0 visible; P1 in flight

  // ---- Phase C: out^T = Wproj @ att^T, weights from staged LDS ----
  f32x4 pacc[2][4];
#pragma unroll
  for (int ti = 0; ti < 2; ++ti)
#pragma unroll
    for (int nj = 0; nj < 4; ++nj) pacc[ti][nj] = f32x4{0.f, 0.f, 0.f, 0.f};

#pragma unroll
  for (int ks = 0; ks < 8; ++ks) {
    const unsigned short* wb = wbuf[ks & 1];
    const int kof = ks * 32 + 8 * g;
    s16x8 bx[4];
#pragma unroll
    for (int nj = 0; nj < 4; ++nj) {
      const int row = 16 * nj + c;
      bx[nj] = *(const s16x8*)&xls[(row * 256 + kof) ^ c7s];
    }
#pragma unroll
    for (int ti = 0; ti < 2; ++ti) {
      s16x8 aw = *(const s16x8*)&wb[wswz((2 * w + ti) * 16 + c, g)];
#pragma unroll
      for (int nj = 0; nj < 4; ++nj)
        pacc[ti][nj] = __builtin_amdgcn_mfma_f32_16x16x32_bf16(aw, bx[nj], pacc[ti][nj], 0, 0, 0);
    }
    if (ks < 7) {
#pragma unroll
      for (int i = 0; i < 2; ++i) {
        const int idx = i * 512 + tid, row = idx >> 2, gl = idx & 3;
        *(s16x8*)&wbuf[(ks + 1) & 1][wswz(row, gl)] = pst[i];
      }
    }
    if (ks < 6) {
#pragma unroll
      for (int i = 0; i < 2; ++i) {
        const int idx = i * 512 + tid, row = idx >> 2, gl = idx & 3;
        pst[i] = *(const s16x8*)&wp_bf[row * 256 + (ks + 2) * 32 + gl * 8];
      }
    }
    bar_lgkm();
  }

  // ---- epilogue: FULL 64KB f32 out-tile over both W buffers, ONE barrier,
  //      then 8 consecutive coalesced NT stores ----
  float* ldsf = (float*)wbuf[0];   // 96KB available; tile needs 64KB
  float* __restrict__ ob = out + (size_t)bn * SD;
#pragma unroll
  for (int ti = 0; ti < 2; ++ti) {
    const int e0 = (2 * w + ti) * 16 + 4 * g;
    f32x4 bp = *(const f32x4*)(bproj + e0);
#pragma unroll
    for (int nj = 0; nj < 4; ++nj) {
      const int lr = 16 * nj + c;   // full row index 0..63
      f32x4 v;
      v[0] = pacc[ti][nj][0] + bp[0];
      v[1] = pacc[ti][nj][1] + bp[1];
      v[2] = pacc[ti][nj][2] + bp[2];
      v[3] = pacc[ti][nj][3] + bp[3];
      *(f32x4*)&ldsf[(lr * 256 + e0) ^ ((lr & 7) << 2)] = v;
    }
  }
  bar_lgkm();
#pragma unroll
  for (int it = 0; it < 8; ++it) {
    const int i = (it * 512 + tid) * 4;   // [0, 16384)
    const int lr = i >> 8;
    f32x4 v = *(const f32x4*)&ldsf[i ^ ((lr & 7) << 2)];
    __builtin_nontemporal_store(v, (f32x4*)(ob + i));
  }
}

extern "C" void kernel_launch(void* const* d_in, const int* in_sizes, int n_in,
                              void* d_out, int out_size, void* d_ws, size_t ws_size,
                              hipStream_t stream) {
  (void)n_in; (void)ws_size; (void)out_size;
  const float* x     = (const float*)d_in[0];
  const float* wqkv  = (const float*)d_in[1];
  const float* bqkv  = (const float*)d_in[2];
  const float* wproj = (const float*)d_in[3];
  const float* bproj = (const float*)d_in[4];
  float* out = (float*)d_out;

  unsigned short* wsb = (unsigned short*)d_ws;
  const unsigned short* wq_bf = wsb;
  const unsigned short* wp_bf = wsb + NQKV;

  hipLaunchKernelGGL(ta_prep_weights, dim3(256), dim3(256), 0, stream, wqkv, wproj, wsb);

  const int bn_total = in_sizes[0] / SD;  // 2600
  hipLaunchKernelGGL(ta_fused_kernel, dim3(bn_total), dim3(512), 0, stream,
                     x, wq_bf, bqkv, wp_bf, bproj, out);
}